// Round 9
// baseline (319.921 us; speedup 1.0000x reference)
//
#include <hip/hip_runtime.h>
#include <cstdint>

typedef unsigned short u16;
typedef uint32_t u32;
typedef __bf16 bf16x8 __attribute__((ext_vector_type(8)));
typedef float f32x4 __attribute__((ext_vector_type(4)));

__device__ __forceinline__ u16 f2bf(float f) {
  unsigned u = __float_as_uint(f);
  u += 0x7fffu + ((u >> 16) & 1u);
  return (u16)(u >> 16);
}

__device__ __forceinline__ void async16(const void* g, void* l) {
  __builtin_amdgcn_global_load_lds(
      (const __attribute__((address_space(1))) uint32_t*)g,
      (__attribute__((address_space(3))) uint32_t*)l, 16, 0, 0);
}

// --- fused prep: x->bf16 | proj_w^T | out_w^T | mask bitpack (one dispatch) ---
__global__ __launch_bounds__(256) void k_prep(const float* __restrict__ x, u16* __restrict__ xb,
                                              const float* __restrict__ pw, u16* __restrict__ wt,
                                              const float* __restrict__ ow, u16* __restrict__ owt,
                                              const int* __restrict__ mask, u32* __restrict__ mbits) {
  const int bid = blockIdx.x;
  if (bid < 8192) {
    const int i = bid * 256 + threadIdx.x;
    const float4 v = ((const float4*)x)[i];
    ushort4 o;
    o.x = f2bf(v.x); o.y = f2bf(v.y); o.z = f2bf(v.z); o.w = f2bf(v.w);
    ((ushort4*)xb)[i] = o;
    return;
  }
  if (bid >= 12288) {
    const size_t w = (size_t)(bid - 12288) * 256 + threadIdx.x;
    const int* p = mask + w * 32;
    u32 bits = 0;
#pragma unroll
    for (int j = 0; j < 8; ++j) {
      const int4 v = ((const int4*)p)[j];
      bits |= (u32)(v.x & 1) << (j * 4 + 0);
      bits |= (u32)(v.y & 1) << (j * 4 + 1);
      bits |= (u32)(v.z & 1) << (j * 4 + 2);
      bits |= (u32)(v.w & 1) << (j * 4 + 3);
    }
    mbits[w] = bits;
    return;
  }
  __shared__ u16 tile[32][33];
  const int tx = threadIdx.x & 31, ty = threadIdx.x >> 5;
  const float* in;
  u16* outp;
  int lda, ldo, c0, r0;
  if (bid < 11264) {
    const int id = bid - 8192;  // proj_w [1024][3072] -> wt [3072][1024]
    c0 = (id % 96) * 32; r0 = (id / 96) * 32;
    in = pw; outp = wt; lda = 3072; ldo = 1024;
  } else {
    const int id = bid - 11264;  // out_w [1024][1024] -> owt
    c0 = (id % 32) * 32; r0 = (id / 32) * 32;
    in = ow; outp = owt; lda = 1024; ldo = 1024;
  }
#pragma unroll
  for (int i = 0; i < 4; ++i)
    tile[ty + i * 8][tx] = f2bf(in[(size_t)(r0 + ty + i * 8) * lda + c0 + tx]);
  __syncthreads();
#pragma unroll
  for (int i = 0; i < 4; ++i)
    outp[(size_t)(c0 + ty + i * 8) * ldo + r0 + tx] = tile[tx][ty + i * 8];
}

// =====================================================================
// 256x128-tile CO-RESIDENT pipelined core (r8 proven; r9 adds MODE 2/3):
// 512 thr = 8 waves (4x2), wave-tile 64x64, 3 LDS bufs x 24 KiB = 72 KiB
// -> 2 blocks/CU at 512-block grids. Depth-2 prefetch, end-of-window
// vmcnt(3), never 0 mid-loop. Compiler-staggered lgkmcnt per MFMA
// first-use; asm s_barrier with "memory" clobber (no hoisting).
// r7 lesson (NaN): global_load_lds imm offset applies to BOTH global and
// LDS addresses -- walk K-tiles via pointers, never the imm field.
// LDS layout: line l = rows {2l,2l+1}; group gg = go^(l&7), go=(row&1)*4+k16
// -> conflict-free (0 measured r2/r6). DMA dest LINEAR; source pre-permuted.
// MODE 0: +bias[col], cols<1024 *1/32, bf16      (qkv)
// MODE 1: mask+exp, bf16                          (P)
// MODE 2: ones-MFMA rowsum, v/rowsum+bias, fp32   (out)
// MODE 3: transposed bf16 store                   (Ut)
// =====================================================================
template <int MODE>
__global__ __launch_bounds__(512, 4) void gemm256(
    const u16* __restrict__ A, long lda, long bsA,
    const u16* __restrict__ Bt, long ldb, long bsB,
    void* __restrict__ C, long ldc, long bsC,
    int M, int N, int K,
    const float* __restrict__ bias, const u32* __restrict__ mbits) {
  __shared__ u16 sm[3][12288];  // [buf][A:8192 | B:4096] u16 = 72 KiB
  const int gx = gridDim.x, gxy = gridDim.x * gridDim.y;
  const int T = gxy * gridDim.z;
  int L = blockIdx.x + gx * blockIdx.y + gxy * blockIdx.z;
  L = (L & 7) * (T >> 3) + (L >> 3);  // XCD swizzle; T divisible by 8
  const int b = L / gxy, rr = L % gxy, bx = rr % gx, by = rr / gx;
  const int m0 = by * 256, n0 = bx * 128;
  const int tid = threadIdx.x;
  const int lane = tid & 63;
  const int w = tid >> 6;
  const int wr = w >> 1, wc = w & 1;  // 4 x 2 waves, wave tile 64x64

  // ---- staging: A slots tid (rows 0..127) / tid+512 (rows 128..255),
  // B slots tid (rows 0..127). slot s: line l=s>>3, gg=s&7, go=gg^(l&7),
  // row = 2l + (go>>2), k-offset = (go&3)*8 u16.
  const int sl = tid >> 3;
  const int sgo = (tid & 7) ^ (sl & 7);
  const int srow = 2 * sl + (sgo >> 2);
  const int skoff = (sgo & 3) * 8;
  const u16* pa = A + (size_t)b * bsA + (size_t)(m0 + srow) * lda + skoff;
  const u16* pb = Bt + (size_t)b * bsB + (size_t)(n0 + srow) * ldb + skoff;
  const size_t a128 = (size_t)128 * lda;

  // ---- fragment read bases (u16): row r, k16=q -> line r>>1,
  // g = ((r&1)*4 + q) ^ ((r>>1)&7), addr = line*64 + g*8.
  const int m_l = lane & 15, q = lane >> 4;
  const int l7 = m_l >> 1;  // (r>>1)&7; mt stride = 16 rows = 8 lines
  const int g = (((m_l & 1) * 4) + q) ^ l7;
  const int aoff = wr * 2048 + l7 * 64 + g * 8;      // wr*64 rows = wr*32 lines
  const int boff = 8192 + wc * 2048 + l7 * 64 + g * 8;  // wc*64 rows

  f32x4 acc[4][4] = {};
  f32x4 accs[4] = {};  // MODE 2 rowsum (dead otherwise)
  bf16x8 ones;
#pragma unroll
  for (int e = 0; e < 8; ++e) ones[e] = (__bf16)1.0f;

#define MFMA_(A_, B_, C_) __builtin_amdgcn_mfma_f32_16x16x32_bf16(A_, B_, C_, 0, 0, 0)
#define STAGE(tt, bi)                               \
  {                                                 \
    const size_t ko_ = (size_t)(tt)*32;             \
    u16* da_ = &sm[bi][0] + tid * 8;                \
    async16(pa + ko_, da_);                         \
    async16(pa + ko_ + a128, da_ + 4096);           \
    async16(pb + ko_, &sm[bi][8192] + tid * 8);     \
  }

  const int NTL = K >> 5;  // K-tiles of 32
  STAGE(0, 0) STAGE(1, 1)
  asm volatile("s_waitcnt vmcnt(3)" ::: "memory");  // tile 0 landed
  asm volatile("s_barrier" ::: "memory");

  int br = 0, bs = 2;  // read buf = t%3, stage buf = (t+2)%3
  for (int t = 0; t < NTL; ++t) {
    if (t + 2 < NTL) STAGE(t + 2, bs)
    const u16* ab = &sm[br][0] + aoff;
    const u16* bb = &sm[br][0] + boff;
    bf16x8 af[4], bf[4];
#pragma unroll
    for (int mt = 0; mt < 4; ++mt) af[mt] = *(const bf16x8*)(ab + mt * 512);
#pragma unroll
    for (int nt = 0; nt < 4; ++nt) bf[nt] = *(const bf16x8*)(bb + nt * 512);
    __builtin_amdgcn_s_setprio(1);
#pragma unroll
    for (int mt = 0; mt < 4; ++mt)
#pragma unroll
      for (int nt = 0; nt < 4; ++nt)
        acc[mt][nt] = MFMA_(af[mt], bf[nt], acc[mt][nt]);
    if constexpr (MODE == 2) {
#pragma unroll
      for (int mt = 0; mt < 4; ++mt)
        accs[mt] = MFMA_(af[mt], ones, accs[mt]);
    }
    __builtin_amdgcn_s_setprio(0);
    if (t + 2 < NTL) {
      asm volatile("s_waitcnt vmcnt(3)" ::: "memory");  // tile t+1 landed
    } else if (t + 1 < NTL) {
      asm volatile("s_waitcnt vmcnt(0)" ::: "memory");
    }
    if (t + 1 < NTL) asm volatile("s_barrier" ::: "memory");
    br = (br == 2) ? 0 : br + 1;
    bs = (bs == 2) ? 0 : bs + 1;
  }
#undef STAGE
#undef MFMA_

  if constexpr (MODE == 1) {
    __syncthreads();
    // mask bits for this tile: 256 rows x 4 words (128 cols)
    u32* smw = (u32*)&sm[0][0];
    const int rl = tid >> 1, pr = tid & 1;
    const uint2 mv = *(const uint2*)(mbits + ((size_t)b * M + m0 + rl) * (N >> 5) + (n0 >> 5) + pr * 2);
    smw[rl * 4 + pr * 2] = mv.x;
    smw[rl * 4 + pr * 2 + 1] = mv.y;
    __syncthreads();
  }

  float rinv[4][4];
  if constexpr (MODE == 2) {
#pragma unroll
    for (int mt = 0; mt < 4; ++mt)
#pragma unroll
      for (int r = 0; r < 4; ++r) rinv[mt][r] = 1.0f / accs[mt][r];
  }

#pragma unroll
  for (int mt = 0; mt < 4; ++mt) {
#pragma unroll
    for (int nt = 0; nt < 4; ++nt) {
      const int col = n0 + wc * 64 + nt * 16 + m_l;
      const int row0 = m0 + wr * 64 + mt * 16 + q * 4;
      if constexpr (MODE == 3) {
        ushort4 o;
        o.x = f2bf(acc[mt][nt][0]); o.y = f2bf(acc[mt][nt][1]);
        o.z = f2bf(acc[mt][nt][2]); o.w = f2bf(acc[mt][nt][3]);
        *(ushort4*)((u16*)C + (size_t)b * bsC + (size_t)col * ldc + row0) = o;
      } else {
#pragma unroll
        for (int r = 0; r < 4; ++r) {
          const int row = row0 + r;
          float v = acc[mt][nt][r];
          if constexpr (MODE == 0) {
            v += bias[col];
            if (col < 1024) v *= 0.03125f;
            ((u16*)C)[(size_t)b * bsC + (size_t)row * ldc + col] = f2bf(v);
          } else if constexpr (MODE == 1) {
            const int cl = wc * 64 + nt * 16 + m_l;
            const int rl2 = wr * 64 + mt * 16 + q * 4 + r;
            const u32 wb = ((const u32*)&sm[0][0])[rl2 * 4 + (cl >> 5)];
            v = ((wb >> (cl & 31)) & 1u) ? __expf(fminf(v, 30.f)) : 0.f;
            ((u16*)C)[(size_t)b * bsC + (size_t)row * ldc + col] = f2bf(v);
          } else if constexpr (MODE == 2) {
            v = v * rinv[mt][r] + bias[col];
            ((float*)C)[(size_t)b * bsC + (size_t)row * ldc + col] = v;
          }
        }
      }
    }
  }
}

extern "C" void kernel_launch(void* const* d_in, const int* in_sizes, int n_in,
                              void* d_out, int out_size, void* d_ws, size_t ws_size,
                              hipStream_t stream) {
  const float* x = (const float*)d_in[0];
  const int* mask = (const int*)d_in[1];
  const float* proj_w = (const float*)d_in[2];
  const float* proj_b = (const float*)d_in[3];
  const float* out_w = (const float*)d_in[4];
  const float* out_b = (const float*)d_in[5];
  float* out = (float*)d_out;

  char* ws = (char*)d_ws;
  u16* xb = (u16*)(ws);                      // 16.8 MB; Ut aliases after qkv
  u16* wt = (u16*)(ws + 16777216);           // 6.3 MB
  u16* owt = (u16*)(ws + 23068672);          // 2.1 MB
  u16* qkv = (u16*)(ws + 25165824);          // 50.3 MB
  u16* P = (u16*)(ws + 75497472);            // 33.6 MB
  u32* mbits = (u32*)(ws + 109051904);       // 2.1 MB
  u16* Ut = (u16*)xb;                        // 16.8 MB [4][1024][2048]

  // 1. prep
  k_prep<<<14336, 256, 0, stream>>>(x, xb, proj_w, wt, out_w, owt, mask, mbits);
  // 2. qkv = x @ proj_w + b (q prescaled 1/32)   T=768 (2 blk/CU)
  gemm256<0><<<dim3(24, 32, 1), 512, 0, stream>>>(
      xb, 1024, 0, wt, 1024, 0, qkv, 3072, 0, 8192, 3072, 1024, proj_b, nullptr);
  // 3. P = mask ? exp(q k^T / 32) : 0            T=512 (2 blk/CU)
  gemm256<1><<<dim3(16, 8, 4), 512, 0, stream>>>(
      qkv, 3072, (long)2048 * 3072, qkv + 1024, 3072, (long)2048 * 3072,
      P, 2048, (long)2048 * 2048, 2048, 2048, 1024, nullptr, mbits);
  // 4. Ut = (V @ out_w)^T                        T=256 (was legacy TM=64)
  gemm256<3><<<dim3(8, 8, 4), 512, 0, stream>>>(
      qkv + 2048, 3072, (long)2048 * 3072, owt, 1024, 0,
      Ut, 2048, (long)1024 * 2048, 2048, 1024, 1024, nullptr, nullptr);
  // 5. out = P @ U / rowsum(P) + out_b           T=256 (was legacy)
  gemm256<2><<<dim3(8, 8, 4), 512, 0, stream>>>(
      P, 2048, (long)2048 * 2048, Ut, 2048, (long)1024 * 2048,
      out, 1024, (long)2048 * 1024, 2048, 1024, 2048, out_b, nullptr);
}

// Round 10
// 313.825 us; speedup vs baseline: 1.0194x; 1.0194x over previous
//
#include <hip/hip_runtime.h>
#include <cstdint>

typedef unsigned short u16;
typedef uint32_t u32;
typedef __bf16 bf16x8 __attribute__((ext_vector_type(8)));
typedef float f32x4 __attribute__((ext_vector_type(4)));

__device__ __forceinline__ u16 f2bf(float f) {
  unsigned u = __float_as_uint(f);
  u += 0x7fffu + ((u >> 16) & 1u);
  return (u16)(u >> 16);
}

__device__ __forceinline__ void async16(const void* g, void* l) {
  __builtin_amdgcn_global_load_lds(
      (const __attribute__((address_space(1))) uint32_t*)g,
      (__attribute__((address_space(3))) uint32_t*)l, 16, 0, 0);
}

// --- fused prep: x->bf16 | proj_w^T | out_w^T | mask bitpack (one dispatch) ---
__global__ __launch_bounds__(256) void k_prep(const float* __restrict__ x, u16* __restrict__ xb,
                                              const float* __restrict__ pw, u16* __restrict__ wt,
                                              const float* __restrict__ ow, u16* __restrict__ owt,
                                              const int* __restrict__ mask, u32* __restrict__ mbits) {
  const int bid = blockIdx.x;
  if (bid < 8192) {
    const int i = bid * 256 + threadIdx.x;
    const float4 v = ((const float4*)x)[i];
    ushort4 o;
    o.x = f2bf(v.x); o.y = f2bf(v.y); o.z = f2bf(v.z); o.w = f2bf(v.w);
    ((ushort4*)xb)[i] = o;
    return;
  }
  if (bid >= 12288) {
    const size_t w = (size_t)(bid - 12288) * 256 + threadIdx.x;
    const int* p = mask + w * 32;
    u32 bits = 0;
#pragma unroll
    for (int j = 0; j < 8; ++j) {
      const int4 v = ((const int4*)p)[j];
      bits |= (u32)(v.x & 1) << (j * 4 + 0);
      bits |= (u32)(v.y & 1) << (j * 4 + 1);
      bits |= (u32)(v.z & 1) << (j * 4 + 2);
      bits |= (u32)(v.w & 1) << (j * 4 + 3);
    }
    mbits[w] = bits;
    return;
  }
  __shared__ u16 tile[32][33];
  const int tx = threadIdx.x & 31, ty = threadIdx.x >> 5;
  const float* in;
  u16* outp;
  int lda, ldo, c0, r0;
  if (bid < 11264) {
    const int id = bid - 8192;  // proj_w [1024][3072] -> wt [3072][1024]
    c0 = (id % 96) * 32; r0 = (id / 96) * 32;
    in = pw; outp = wt; lda = 3072; ldo = 1024;
  } else {
    const int id = bid - 11264;  // out_w [1024][1024] -> owt
    c0 = (id % 32) * 32; r0 = (id / 32) * 32;
    in = ow; outp = owt; lda = 1024; ldo = 1024;
  }
#pragma unroll
  for (int i = 0; i < 4; ++i)
    tile[ty + i * 8][tx] = f2bf(in[(size_t)(r0 + ty + i * 8) * lda + c0 + tx]);
  __syncthreads();
#pragma unroll
  for (int i = 0; i < 4; ++i)
    outp[(size_t)(c0 + ty + i * 8) * ldo + r0 + tx] = tile[tx][ty + i * 8];
}

// =====================================================================
// 256x128-tile co-resident pipelined core (r8/r9 proven), refactored as
// an inlinable device function so independent GEMMs can be horizontally
// fused into one dispatch (shared LDS declared by the CALLER: two inlined
// __shared__ instances would cost 144 KiB and kill 2-block occupancy).
// 512 thr = 8 waves (4x2), wave-tile 64x64, 3 LDS bufs x 24 KiB = 72 KiB,
// depth-2 prefetch, end-of-window vmcnt(3) (never 0 mid-loop), compiler-
// staggered lgkmcnt per MFMA first-use, asm s_barrier w/ "memory" clobber.
// r7 lesson (NaN): global_load_lds imm offset applies to BOTH global and
// LDS addresses -- walk K-tiles via pointers, never the imm field.
// LDS layout: line l = rows {2l,2l+1}; group gg = go^(l&7), go=(row&1)*4+k16
// -> conflict-free (0 measured r2/r6). DMA dest LINEAR; source pre-permuted.
// MODE 0: +bias[col], cols<1024 *1/32, bf16      (qkv)
// MODE 1: mask+exp, bf16                          (P)
// MODE 2: ones-MFMA rowsum, v/rowsum+bias, fp32   (out)
// MODE 3: transposed bf16 store                   (Ut)
// =====================================================================
template <int MODE>
__device__ __forceinline__ void core256(
    u16* __restrict__ smb,  // caller's __shared__ u16[3*12288]
    const u16* __restrict__ A, long lda, long bsA,
    const u16* __restrict__ Bt, long ldb, long bsB,
    void* __restrict__ C, long ldc, long bsC,
    int M, int N, int K,
    const float* __restrict__ bias, const u32* __restrict__ mbits,
    int b, int bx, int by) {
  const int m0 = by * 256, n0 = bx * 128;
  const int tid = threadIdx.x;
  const int lane = tid & 63;
  const int w = tid >> 6;
  const int wr = w >> 1, wc = w & 1;  // 4 x 2 waves, wave tile 64x64

  // staging: slot s: line l=s>>3, gg=s&7, go=gg^(l&7),
  // row = 2l + (go>>2) (+128 for A call 2), k-offset = (go&3)*8 u16.
  const int sl = tid >> 3;
  const int sgo = (tid & 7) ^ (sl & 7);
  const int srow = 2 * sl + (sgo >> 2);
  const int skoff = (sgo & 3) * 8;
  const u16* pa = A + (size_t)b * bsA + (size_t)(m0 + srow) * lda + skoff;
  const u16* pb = Bt + (size_t)b * bsB + (size_t)(n0 + srow) * ldb + skoff;
  const size_t a128 = (size_t)128 * lda;

  // fragment read bases (u16): row r, k16=q -> line r>>1,
  // g = ((r&1)*4 + q) ^ ((r>>1)&7), addr = line*64 + g*8.
  const int m_l = lane & 15, q = lane >> 4;
  const int l7 = m_l >> 1;
  const int g = (((m_l & 1) * 4) + q) ^ l7;
  const int aoff = wr * 2048 + l7 * 64 + g * 8;
  const int boff = 8192 + wc * 2048 + l7 * 64 + g * 8;

  f32x4 acc[4][4] = {};
  f32x4 accs[4] = {};  // MODE 2 rowsum (dead otherwise)
  bf16x8 ones;
#pragma unroll
  for (int e = 0; e < 8; ++e) ones[e] = (__bf16)1.0f;

#define MFMA_(A_, B_, C_) __builtin_amdgcn_mfma_f32_16x16x32_bf16(A_, B_, C_, 0, 0, 0)
#define STAGE(tt, bi)                                   \
  {                                                     \
    const size_t ko_ = (size_t)(tt)*32;                 \
    u16* da_ = smb + (bi)*12288 + tid * 8;              \
    async16(pa + ko_, da_);                             \
    async16(pa + ko_ + a128, da_ + 4096);               \
    async16(pb + ko_, smb + (bi)*12288 + 8192 + tid * 8); \
  }

  const int NTL = K >> 5;  // K-tiles of 32
  STAGE(0, 0) STAGE(1, 1)
  asm volatile("s_waitcnt vmcnt(3)" ::: "memory");  // tile 0 landed
  asm volatile("s_barrier" ::: "memory");

  int br = 0, bs = 2;  // read buf = t%3, stage buf = (t+2)%3
  for (int t = 0; t < NTL; ++t) {
    if (t + 2 < NTL) STAGE(t + 2, bs)
    const u16* ab = smb + br * 12288 + aoff;
    const u16* bb = smb + br * 12288 + boff;
    bf16x8 af[4], bf[4];
#pragma unroll
    for (int mt = 0; mt < 4; ++mt) af[mt] = *(const bf16x8*)(ab + mt * 512);
#pragma unroll
    for (int nt = 0; nt < 4; ++nt) bf[nt] = *(const bf16x8*)(bb + nt * 512);
    __builtin_amdgcn_s_setprio(1);
#pragma unroll
    for (int mt = 0; mt < 4; ++mt)
#pragma unroll
      for (int nt = 0; nt < 4; ++nt)
        acc[mt][nt] = MFMA_(af[mt], bf[nt], acc[mt][nt]);
    if constexpr (MODE == 2) {
#pragma unroll
      for (int mt = 0; mt < 4; ++mt)
        accs[mt] = MFMA_(af[mt], ones, accs[mt]);
    }
    __builtin_amdgcn_s_setprio(0);
    if (t + 2 < NTL) {
      asm volatile("s_waitcnt vmcnt(3)" ::: "memory");  // tile t+1 landed
    } else if (t + 1 < NTL) {
      asm volatile("s_waitcnt vmcnt(0)" ::: "memory");
    }
    if (t + 1 < NTL) asm volatile("s_barrier" ::: "memory");
    br = (br == 2) ? 0 : br + 1;
    bs = (bs == 2) ? 0 : bs + 1;
  }
#undef STAGE
#undef MFMA_

  if constexpr (MODE == 1) {
    __syncthreads();
    // mask bits for this tile: 256 rows x 4 words (128 cols)
    u32* smw = (u32*)smb;
    const int rl = tid >> 1, pr = tid & 1;
    const uint2 mv = *(const uint2*)(mbits + ((size_t)b * M + m0 + rl) * (N >> 5) + (n0 >> 5) + pr * 2);
    smw[rl * 4 + pr * 2] = mv.x;
    smw[rl * 4 + pr * 2 + 1] = mv.y;
    __syncthreads();
  }

  float rinv[4][4];
  if constexpr (MODE == 2) {
#pragma unroll
    for (int mt = 0; mt < 4; ++mt)
#pragma unroll
      for (int r = 0; r < 4; ++r) rinv[mt][r] = 1.0f / accs[mt][r];
  }

#pragma unroll
  for (int mt = 0; mt < 4; ++mt) {
#pragma unroll
    for (int nt = 0; nt < 4; ++nt) {
      const int col = n0 + wc * 64 + nt * 16 + m_l;
      const int row0 = m0 + wr * 64 + mt * 16 + q * 4;
      if constexpr (MODE == 3) {
        ushort4 o;
        o.x = f2bf(acc[mt][nt][0]); o.y = f2bf(acc[mt][nt][1]);
        o.z = f2bf(acc[mt][nt][2]); o.w = f2bf(acc[mt][nt][3]);
        *(ushort4*)((u16*)C + (size_t)b * bsC + (size_t)col * ldc + row0) = o;
      } else {
#pragma unroll
        for (int r = 0; r < 4; ++r) {
          const int row = row0 + r;
          float v = acc[mt][nt][r];
          if constexpr (MODE == 0) {
            v += bias[col];
            if (col < 1024) v *= 0.03125f;
            ((u16*)C)[(size_t)b * bsC + (size_t)row * ldc + col] = f2bf(v);
          } else if constexpr (MODE == 1) {
            const int cl = wc * 64 + nt * 16 + m_l;
            const int rl2 = wr * 64 + mt * 16 + q * 4 + r;
            const u32 wb = ((const u32*)smb)[rl2 * 4 + (cl >> 5)];
            v = ((wb >> (cl & 31)) & 1u) ? __expf(fminf(v, 30.f)) : 0.f;
            ((u16*)C)[(size_t)b * bsC + (size_t)row * ldc + col] = f2bf(v);
          } else if constexpr (MODE == 2) {
            v = v * rinv[mt][r] + bias[col];
            ((float*)C)[(size_t)b * bsC + (size_t)row * ldc + col] = v;
          }
        }
      }
    }
  }
}

// standalone wrapper (steps 2 and 5)
template <int MODE>
__global__ __launch_bounds__(512, 4) void gemm256(
    const u16* __restrict__ A, long lda, long bsA,
    const u16* __restrict__ Bt, long ldb, long bsB,
    void* __restrict__ C, long ldc, long bsC,
    int M, int N, int K,
    const float* __restrict__ bias, const u32* __restrict__ mbits) {
  __shared__ u16 sm[3][12288];
  const int gx = gridDim.x, gxy = gridDim.x * gridDim.y;
  const int T = gxy * gridDim.z;
  int L = blockIdx.x + gx * blockIdx.y + gxy * blockIdx.z;
  L = (L & 7) * (T >> 3) + (L >> 3);  // XCD swizzle; T divisible by 8
  const int b = L / gxy, rr = L % gxy;
  core256<MODE>(&sm[0][0], A, lda, bsA, Bt, ldb, bsB, C, ldc, bsC, M, N, K,
                bias, mbits, b, rr % gx, rr / gx);
}

// horizontal fusion of step 3 (P = mask?exp(qk^T/32):0, 512 blocks) and
// step 4 (Ut = (V @ out_w)^T, 256 blocks) -- mutually independent, both
// read only qkv+owt. Packs s4's blocks into the CU slots that idled at
// 1 blk/CU, and drops one launch gap. Block-uniform branch, shared LDS.
__global__ __launch_bounds__(512, 4) void k_fused34(
    const u16* __restrict__ qkv, const u16* __restrict__ owt,
    u16* __restrict__ P, u16* __restrict__ Ut, const u32* __restrict__ mbits) {
  __shared__ u16 sm[3][12288];
  int L = blockIdx.x;
  L = (L & 7) * (768 >> 3) + (L >> 3);  // XCD swizzle over T=768
  if (L < 512) {
    const int bz = L >> 7, r = L & 127;  // s3 grid 16x8x4
    core256<1>(&sm[0][0], qkv, 3072, (long)2048 * 3072, qkv + 1024, 3072,
               (long)2048 * 3072, P, 2048, (long)2048 * 2048, 2048, 2048, 1024,
               nullptr, mbits, bz, r & 15, r >> 4);
  } else {
    const int L4 = L - 512;
    const int bz = L4 >> 6, r = L4 & 63;  // s4 grid 8x8x4
    core256<3>(&sm[0][0], qkv + 2048, 3072, (long)2048 * 3072, owt, 1024, 0,
               Ut, 2048, (long)1024 * 2048, 2048, 1024, 1024,
               nullptr, nullptr, bz, r & 7, r >> 3);
  }
}

extern "C" void kernel_launch(void* const* d_in, const int* in_sizes, int n_in,
                              void* d_out, int out_size, void* d_ws, size_t ws_size,
                              hipStream_t stream) {
  const float* x = (const float*)d_in[0];
  const int* mask = (const int*)d_in[1];
  const float* proj_w = (const float*)d_in[2];
  const float* proj_b = (const float*)d_in[3];
  const float* out_w = (const float*)d_in[4];
  const float* out_b = (const float*)d_in[5];
  float* out = (float*)d_out;

  char* ws = (char*)d_ws;
  u16* xb = (u16*)(ws);                      // 16.8 MB; Ut aliases after qkv
  u16* wt = (u16*)(ws + 16777216);           // 6.3 MB
  u16* owt = (u16*)(ws + 23068672);          // 2.1 MB
  u16* qkv = (u16*)(ws + 25165824);          // 50.3 MB
  u16* P = (u16*)(ws + 75497472);            // 33.6 MB
  u32* mbits = (u32*)(ws + 109051904);       // 2.1 MB
  u16* Ut = (u16*)xb;                        // 16.8 MB [4][1024][2048]

  // 1. prep
  k_prep<<<14336, 256, 0, stream>>>(x, xb, proj_w, wt, out_w, owt, mask, mbits);
  // 2. qkv = x @ proj_w + b (q prescaled 1/32)   T=768 (2 blk/CU)
  gemm256<0><<<dim3(24, 32, 1), 512, 0, stream>>>(
      xb, 1024, 0, wt, 1024, 0, qkv, 3072, 0, 8192, 3072, 1024, proj_b, nullptr);
  // 3+4. P = mask?exp(qk^T/32):0  ||  Ut = (V@out_w)^T   T=768 fused
  k_fused34<<<768, 512, 0, stream>>>(qkv, owt, P, Ut, mbits);
  // 5. out = P @ U / rowsum(P) + out_b           T=256
  gemm256<2><<<dim3(8, 8, 4), 512, 0, stream>>>(
      P, 2048, (long)2048 * 2048, Ut, 2048, (long)1024 * 2048,
      out, 1024, (long)2048 * 1024, 2048, 1024, 2048, out_b, nullptr);
}